// Round 3
// baseline (281.671 us; speedup 1.0000x reference)
//
#include <hip/hip_runtime.h>

typedef unsigned short u16;
typedef unsigned int u32;
typedef __attribute__((ext_vector_type(4))) float float4v;

// One block = one 2x2 window (4 tokens x 256 ch), 128 threads = 2 waves.
// Compute lane mapping: variant v = (t>=64)*2 + ((t&63)>=32); tok=(lane>>3)&3; h=lane&7.
__global__ __launch_bounds__(128) void cattn_kernel(
    const float* __restrict__ rr, const float* __restrict__ gg,
    const float* __restrict__ bb, const float* __restrict__ ii,
    const float* __restrict__ w0, const float* __restrict__ b0,
    const float* __restrict__ w1, const float* __restrict__ b1,
    const float* __restrict__ w2, const float* __restrict__ b2,
    const float* __restrict__ w3, const float* __restrict__ b3,
    float* __restrict__ out)
{
    // [tensor][token][64 float4-chunks], chunk index XOR-swizzled: c4 ^ ((c4>>3)&7)
    __shared__ float sm[4 * 4 * 256];        // 16 KB
    float4v* SM4 = (float4v*)sm;

    const int t   = threadIdx.x;
    const int wid = blockIdx.x;              // 0..8191
    const int bi  = wid >> 10;
    const int rem = wid & 1023;
    const int wy  = rem >> 5, wx = rem & 31;
    const int y0  = wy << 1,  x0 = wx << 1;

    // ---------- stage: global -> LDS (fp32, coalesced float4, swizzled) ----------
    {
        const int c4  = t & 63;              // float4 chunk within a 256-ch row
        const int thi = t >> 6;              // 0/1 -> dx of token
        const int sw  = c4 ^ ((c4 >> 3) & 7);
        // token = (kk&1)*2 + thi  ->  dy = kk&1, dx = thi
        const size_t r0 = ((((size_t)(bi * 64 + y0    )) * 64) + (size_t)(x0 + thi)) * 256;
        const size_t r1 = ((((size_t)(bi * 64 + y0 + 1)) * 64) + (size_t)(x0 + thi)) * 256;
        const float* srcs[4] = { rr, gg, bb, ii };
        #pragma unroll
        for (int kk = 0; kk < 8; ++kk) {
            const int tensor = kk >> 1;                  // constant after unroll
            const int token  = ((kk & 1) << 1) | thi;
            const size_t row = (kk & 1) ? r1 : r0;
            float4v val = *(const float4v*)(srcs[tensor] + row + (size_t)(c4 << 2));
            SM4[tensor * 256 + token * 64 + sw] = val;
        }
    }
    __syncthreads();

    // ---------- compute ----------
    const int lane = t & 63;
    const int vloc = lane >> 5;
    const int v    = ((t >> 6) << 1) | vloc;     // variant 0..3
    const int tok  = (lane >> 3) & 3;            // query token
    const int h    = lane & 7;                   // head

    const int qt  = v;
    const int kvt = (v == 3) ? 1 : (v + 1);      // kv tensor: g,b,ir,g  (K == V)

    const int qbase = qt * 256 + tok * 64 + h * 8;
    const int kbase = kvt * 256 + h * 8;         // + tk*64 + (j^h)

    // q fragment (also the residual)
    float q[32];
    #pragma unroll
    for (int j = 0; j < 8; ++j) {
        float4v c = SM4[qbase + (j ^ h)];
        #pragma unroll
        for (int e = 0; e < 4; ++e) q[j * 4 + e] = c[e];
    }

    // pass 1: scores
    float s[4] = {0.f, 0.f, 0.f, 0.f};
    #pragma unroll
    for (int j = 0; j < 8; ++j) {
        #pragma unroll
        for (int tk = 0; tk < 4; ++tk) {
            float4v c = SM4[kbase + tk * 64 + (j ^ h)];
            s[tk] += q[j*4+0]*c[0] + q[j*4+1]*c[1] + q[j*4+2]*c[2] + q[j*4+3]*c[3];
        }
    }
    #pragma unroll
    for (int tk = 0; tk < 4; ++tk) s[tk] *= 0.17677669529663687f;  // 1/sqrt(32)

    // softmax over 4
    float mx = fmaxf(fmaxf(s[0], s[1]), fmaxf(s[2], s[3]));
    float p[4];
    #pragma unroll
    for (int tk = 0; tk < 4; ++tk) p[tk] = __expf(s[tk] - mx);
    const float inv = 1.f / (p[0] + p[1] + p[2] + p[3]);
    #pragma unroll
    for (int tk = 0; tk < 4; ++tk) p[tk] *= inv;

    // pass 2: o = residual(q) + P·V
    float o[32];
    #pragma unroll
    for (int c = 0; c < 32; ++c) o[c] = q[c];
    #pragma unroll
    for (int tk = 0; tk < 4; ++tk) {
        const float pj = p[tk];
        #pragma unroll
        for (int j = 0; j < 8; ++j) {
            float4v c = SM4[kbase + tk * 64 + (j ^ h)];
            #pragma unroll
            for (int e = 0; e < 4; ++e) o[j * 4 + e] += pj * c[e];
        }
    }

    // LayerNorm over 256 ch: reduce across the 8 head-lanes (lane bits 0-2)
    float sum = 0.f, sq = 0.f;
    #pragma unroll
    for (int c = 0; c < 32; ++c) { sum += o[c]; sq += o[c] * o[c]; }
    #pragma unroll
    for (int off = 1; off < 8; off <<= 1) {
        sum += __shfl_xor(sum, off, 64);
        sq  += __shfl_xor(sq,  off, 64);
    }
    const float mu  = sum * (1.f / 256.f);
    const float var = sq * (1.f / 256.f) - mu * mu;
    const float rs  = rsqrtf(var + 1e-5f);

    const float* lw = (v & 2) ? ((v & 1) ? w3 : w2) : ((v & 1) ? w1 : w0);
    const float* lb = (v & 2) ? ((v & 1) ? b3 : b2) : ((v & 1) ? b1 : b0);
    lw += h * 32;
    lb += h * 32;

    const int dy = tok >> 1, dx = tok & 1;
    const size_t obase =
        ((((size_t)(bi * 64 + y0 + dy)) * 64) + (size_t)(x0 + dx)) * 1024
        + (size_t)(v << 8) + (size_t)(h << 5);

    #pragma unroll
    for (int k = 0; k < 4; ++k) {
        float4v wv0 = *(const float4v*)(lw + k * 8);
        float4v wv1 = *(const float4v*)(lw + k * 8 + 4);
        float4v bv0 = *(const float4v*)(lb + k * 8);
        float4v bv1 = *(const float4v*)(lb + k * 8 + 4);
        float4v ov0, ov1;
        #pragma unroll
        for (int e = 0; e < 4; ++e) {
            ov0[e] = (o[k * 8 + e]     - mu) * rs * wv0[e] + bv0[e];
            ov1[e] = (o[k * 8 + 4 + e] - mu) * rs * wv1[e] + bv1[e];
        }
        *(float4v*)(out + obase + (size_t)(k * 8))     = ov0;
        *(float4v*)(out + obase + (size_t)(k * 8 + 4)) = ov1;
    }
}

extern "C" void kernel_launch(void* const* d_in, const int* in_sizes, int n_in,
                              void* d_out, int out_size, void* d_ws, size_t ws_size,
                              hipStream_t stream) {
    (void)in_sizes; (void)n_in; (void)d_ws; (void)ws_size; (void)out_size;
    const float* rr = (const float*)d_in[0];
    const float* gg = (const float*)d_in[1];
    const float* bb = (const float*)d_in[2];
    const float* ii = (const float*)d_in[3];
    const float* w0 = (const float*)d_in[4];
    const float* b0 = (const float*)d_in[5];
    const float* w1 = (const float*)d_in[6];
    const float* b1 = (const float*)d_in[7];
    const float* w2 = (const float*)d_in[8];
    const float* b2 = (const float*)d_in[9];
    const float* w3 = (const float*)d_in[10];
    const float* b3 = (const float*)d_in[11];
    float* out = (float*)d_out;

    // 8 batches * 32 * 32 windows = 8192 blocks, 128 threads each
    cattn_kernel<<<8192, 128, 0, stream>>>(rr, gg, bb, ii,
                                           w0, b0, w1, b1, w2, b2, w3, b3, out);
}

// Round 4
// 261.933 us; speedup vs baseline: 1.0754x; 1.0754x over previous
//
#include <hip/hip_runtime.h>

typedef __attribute__((ext_vector_type(4))) float float4v;

#define NBLK 2048
#define NWIN 8192

// Persistent blocks: 2048 blocks x 128 threads, 4 windows each, double-buffered
// async staging via global_load_lds (16B). LDS chunk swizzle sw(c)=c^((c>>3)&7)
// is an involution, applied on the GLOBAL side (per-lane address) since the LDS
// destination of global_load_lds is fixed at wavebase + lane*16.
__global__ __launch_bounds__(128) void cattn_kernel(
    const float* __restrict__ rr, const float* __restrict__ gg,
    const float* __restrict__ bb, const float* __restrict__ ii,
    const float* __restrict__ w0, const float* __restrict__ b0,
    const float* __restrict__ w1, const float* __restrict__ b1,
    const float* __restrict__ w2, const float* __restrict__ b2,
    const float* __restrict__ w3, const float* __restrict__ b3,
    float* __restrict__ out)
{
    __shared__ float sm[2 * 4096];           // two 16 KB window buffers
    float4v* SM4 = (float4v*)sm;

    const int t   = threadIdx.x;
    const int wvi = t >> 6;                  // wave 0/1
    const int l   = t & 63;
    const int c4g = l ^ ((l >> 3) & 7);      // global float4-chunk this lane fetches

    // compute-lane mapping
    const int vloc = l >> 5;
    const int v    = (wvi << 1) | vloc;      // variant 0..3
    const int tok  = (l >> 3) & 3;           // query token
    const int h    = l & 7;                  // head
    const int qt   = v;
    const int kvt  = (v == 3) ? 1 : (v + 1); // kv tensor: g,b,ir,g (K==V)

    // hoisted LN params (uniform across windows)
    const float* lw = (v & 2) ? ((v & 1) ? w3 : w2) : ((v & 1) ? w1 : w0);
    const float* lb = (v & 2) ? ((v & 1) ? b3 : b2) : ((v & 1) ? b1 : b0);
    lw += h * 32; lb += h * 32;
    float4v wp[8], bp[8];
    #pragma unroll
    for (int k = 0; k < 8; ++k) {
        wp[k] = *(const float4v*)(lw + k * 4);
        bp[k] = *(const float4v*)(lb + k * 4);
    }

    const float* srcs[4] = { rr, gg, bb, ii };

    // async stage one window into LDS buffer `buf`
    auto issue = [&](int buf, int wid) {
        const int bi  = wid >> 10;
        const int rem = wid & 1023;
        const int y0  = (rem >> 5) << 1;
        const int x0  = (rem & 31) << 1;
        #pragma unroll
        for (int kk = 0; kk < 8; ++kk) {
            // tensor = kk>>1 (CT), dy = kk&1 (CT), dx = wvi (wave-uniform)
            const float* g = srcs[kk >> 1]
                + (((size_t)(bi * 64 + y0 + (kk & 1))) * 64 + (size_t)(x0 + wvi)) * 256
                + (size_t)(c4g << 2);
            float* ldst = sm + buf * 4096 + (((kk << 1) | wvi) << 8);
            __builtin_amdgcn_global_load_lds(
                (const __attribute__((address_space(1))) void*)g,
                (__attribute__((address_space(3))) void*)ldst,
                16, 0, 0);
        }
    };

    int wid = blockIdx.x;                    // 4 windows: wid, +2048, +4096, +6144
    issue(0, wid);
    int cur = 0;

    #pragma unroll
    for (int it = 0; it < 4; ++it, wid += NBLK) {
        __syncthreads();                     // drains vmcnt -> buf[cur] ready
        if (it < 3) issue(cur ^ 1, wid + NBLK);   // prefetch next window (async)

        // ---------- compute window `wid` from buf[cur] ----------
        const int bi  = wid >> 10;
        const int rem = wid & 1023;
        const int y0  = (rem >> 5) << 1;
        const int x0  = (rem & 31) << 1;

        const int bb4   = cur << 10;                       // buf offset in chunks
        const int qbase = bb4 + qt * 256 + tok * 64 + h * 8;
        const int kbase = bb4 + kvt * 256 + h * 8;

        // q fragment (also the residual)
        float q[32];
        #pragma unroll
        for (int j = 0; j < 8; ++j) {
            float4v c = SM4[qbase + (j ^ h)];
            #pragma unroll
            for (int e = 0; e < 4; ++e) q[j * 4 + e] = c[e];
        }

        // pass 1: scores
        float s[4] = {0.f, 0.f, 0.f, 0.f};
        #pragma unroll
        for (int j = 0; j < 8; ++j) {
            #pragma unroll
            for (int tk = 0; tk < 4; ++tk) {
                float4v c = SM4[kbase + tk * 64 + (j ^ h)];
                s[tk] += q[j*4+0]*c[0] + q[j*4+1]*c[1] + q[j*4+2]*c[2] + q[j*4+3]*c[3];
            }
        }
        #pragma unroll
        for (int tk = 0; tk < 4; ++tk) s[tk] *= 0.17677669529663687f;  // 1/sqrt(32)

        // softmax over 4
        float mx = fmaxf(fmaxf(s[0], s[1]), fmaxf(s[2], s[3]));
        float p[4];
        #pragma unroll
        for (int tk = 0; tk < 4; ++tk) p[tk] = __expf(s[tk] - mx);
        const float inv = 1.f / (p[0] + p[1] + p[2] + p[3]);
        #pragma unroll
        for (int tk = 0; tk < 4; ++tk) p[tk] *= inv;

        // pass 2: o = residual(q) + P·V
        float o[32];
        #pragma unroll
        for (int c = 0; c < 32; ++c) o[c] = q[c];
        #pragma unroll
        for (int tk = 0; tk < 4; ++tk) {
            const float pj = p[tk];
            #pragma unroll
            for (int j = 0; j < 8; ++j) {
                float4v c = SM4[kbase + tk * 64 + (j ^ h)];
                #pragma unroll
                for (int e = 0; e < 4; ++e) o[j * 4 + e] += pj * c[e];
            }
        }

        // LayerNorm over 256 ch: reduce across the 8 head-lanes
        float sum = 0.f, sq = 0.f;
        #pragma unroll
        for (int c = 0; c < 32; ++c) { sum += o[c]; sq += o[c] * o[c]; }
        #pragma unroll
        for (int off = 1; off < 8; off <<= 1) {
            sum += __shfl_xor(sum, off, 64);
            sq  += __shfl_xor(sq,  off, 64);
        }
        const float mu  = sum * (1.f / 256.f);
        const float var = sq * (1.f / 256.f) - mu * mu;
        const float rs  = rsqrtf(var + 1e-5f);

        const int dy = tok >> 1, dx = tok & 1;
        const size_t obase =
            ((((size_t)(bi * 64 + y0 + dy)) * 64) + (size_t)(x0 + dx)) * 1024
            + (size_t)(v << 8) + (size_t)(h << 5);

        #pragma unroll
        for (int k = 0; k < 4; ++k) {
            float4v ov0, ov1;
            #pragma unroll
            for (int e = 0; e < 4; ++e) {
                ov0[e] = (o[k * 8 + e]     - mu) * rs * wp[2*k][e]   + bp[2*k][e];
                ov1[e] = (o[k * 8 + 4 + e] - mu) * rs * wp[2*k+1][e] + bp[2*k+1][e];
            }
            *(float4v*)(out + obase + (size_t)(k * 8))     = ov0;
            *(float4v*)(out + obase + (size_t)(k * 8 + 4)) = ov1;
        }

        cur ^= 1;
    }
}

extern "C" void kernel_launch(void* const* d_in, const int* in_sizes, int n_in,
                              void* d_out, int out_size, void* d_ws, size_t ws_size,
                              hipStream_t stream) {
    (void)in_sizes; (void)n_in; (void)d_ws; (void)ws_size; (void)out_size;
    const float* rr = (const float*)d_in[0];
    const float* gg = (const float*)d_in[1];
    const float* bb = (const float*)d_in[2];
    const float* ii = (const float*)d_in[3];
    const float* w0 = (const float*)d_in[4];
    const float* b0 = (const float*)d_in[5];
    const float* w1 = (const float*)d_in[6];
    const float* b1 = (const float*)d_in[7];
    const float* w2 = (const float*)d_in[8];
    const float* b2 = (const float*)d_in[9];
    const float* w3 = (const float*)d_in[10];
    const float* b3 = (const float*)d_in[11];
    float* out = (float*)d_out;

    cattn_kernel<<<NBLK, 128, 0, stream>>>(rr, gg, bb, ii,
                                           w0, b0, w1, b1, w2, b2, w3, b3, out);
}